// Round 7
// baseline (193.024 us; speedup 1.0000x reference)
//
#include <hip/hip_runtime.h>
#include <stdint.h>

#define N_ROWS 32768
#define D_CLS  1000
#define D_PAD  1024
#define F_DIM  300
#define F_PAD  320
#define MARGIN 0.1f

// ---- fused16 params ----
#define M16    16                    // rows per block
#define F16THR 512                   // 8 waves
#define LDA    328                   // A LDS row stride (uint16 units)
#define SRW    18                    // S LDS col stride (16 rows + 2 pad, uint16)
#define A_OFF  (D_PAD * SRW - M16 * LDA)   // A staged at LDS tail (13184)

#define NPART  32                    // reduce stage-1 blocks

typedef short short8 __attribute__((ext_vector_type(8)));
typedef float f32x4  __attribute__((ext_vector_type(4)));

__device__ __forceinline__ uint32_t rotl32(uint32_t x, int r) {
  return (x << r) | (x >> (32 - r));
}

// JAX threefry2x32 (20 rounds) — bit-exact
__device__ __forceinline__ void threefry2x32(uint32_t k0, uint32_t k1,
                                             uint32_t x0, uint32_t x1,
                                             uint32_t& o0, uint32_t& o1) {
  uint32_t k2 = k0 ^ k1 ^ 0x1BD11BDAu;
  x0 += k0; x1 += k1;
#define TF_R(r) { x0 += x1; x1 = rotl32(x1, (r)); x1 ^= x0; }
  TF_R(13) TF_R(15) TF_R(26) TF_R(6)
  x0 += k1; x1 += k2 + 1u;
  TF_R(17) TF_R(29) TF_R(16) TF_R(24)
  x0 += k2; x1 += k0 + 2u;
  TF_R(13) TF_R(15) TF_R(26) TF_R(6)
  x0 += k0; x1 += k1 + 3u;
  TF_R(17) TF_R(29) TF_R(16) TF_R(24)
  x0 += k1; x1 += k2 + 4u;
  TF_R(13) TF_R(15) TF_R(26) TF_R(6)
  x0 += k2; x1 += k0 + 5u;
#undef TF_R
  o0 = x0; o1 = x1;
}

// Hoisted-schedule threefry (r17-verified, same bits); keys live in SGPRs
// when constructed from readfirstlane'd (wave-uniform) subkeys.
struct TFSched {
  uint32_t k0, k1, k2, k2p1, k0p2, k1p3, k2p4, k0p5;
};
__device__ __forceinline__ TFSched tf_make(uint32_t k0, uint32_t k1) {
  TFSched s;
  s.k0 = k0; s.k1 = k1;
  s.k2 = k0 ^ k1 ^ 0x1BD11BDAu;
  s.k2p1 = s.k2 + 1u; s.k0p2 = k0 + 2u; s.k1p3 = k1 + 3u;
  s.k2p4 = s.k2 + 4u; s.k0p5 = k0 + 5u;
  return s;
}
__device__ __forceinline__ uint32_t tf_hash(const TFSched& s, uint32_t c) {
  uint32_t x0 = s.k0, x1 = c + s.k1;
#define TFH(r) { x0 += x1; x1 = __builtin_amdgcn_alignbit(x1, x1, 32 - (r)); x1 ^= x0; }
  TFH(13) TFH(15) TFH(26) TFH(6)
  x0 += s.k1; x1 += s.k2p1;
  TFH(17) TFH(29) TFH(16) TFH(24)
  x0 += s.k2; x1 += s.k0p2;
  TFH(13) TFH(15) TFH(26) TFH(6)
  x0 += s.k0; x1 += s.k1p3;
  TFH(17) TFH(29) TFH(16) TFH(24)
  x0 += s.k1; x1 += s.k2p4;
  TFH(13) TFH(15) TFH(26) TFH(6)
  x0 += s.k2; x1 += s.k0p5;
#undef TFH
  return x0 ^ x1;
}

__device__ __forceinline__ uint16_t f2bf(float f) {   // RNE fp32 -> bf16
  uint32_t u = __builtin_bit_cast(uint32_t, f);
  return (uint16_t)((u + 0x7FFFu + ((u >> 16) & 1u)) >> 16);
}
__device__ __forceinline__ float bf2f(uint16_t v) {
  return __builtin_bit_cast(float, (uint32_t)v << 16);
}
__device__ __forceinline__ float bf2f_lo(uint32_t v) {
  return __builtin_bit_cast(float, v << 16);
}
__device__ __forceinline__ float bf2f_hi(uint32_t v) {
  return __builtin_bit_cast(float, v & 0xFFFF0000u);
}

// prep: Y fp32 -> Ybf bf16 (zero-padded)
__global__ void prep(const float* __restrict__ Y, uint16_t* __restrict__ Ybf) {
  int i = blockIdx.x * 256 + threadIdx.x;
  if (i < D_PAD * F_PAD) {
    int j = i / F_PAD;
    int k = i - j * F_PAD;
    float v = (j < D_CLS && k < F_DIM) ? Y[j * F_DIM + k] : 0.f;
    Ybf[i] = f2bf(v);
  }
}

// ====== fused16: GEMM -> S in LDS -> hash+loss, 4 blocks/CU ======
// 2048 blocks x 512 thr (8 waves).  LDS = S matrix [1024 cols][SRW=18] bf16
// (36.9KB) -> 4 blocks/CU = 32 waves/CU.  A (16 rows, bf16) staged into the
// TAIL of the same buffer; S cols 0..511 never touch it, S cols 512..1023
// overwrite it only after a barrier (acc held in regs across it) -> peak
// live acc = 16 VGPRs, whole kernel fits the 64-VGPR/8-waves-per-EU budget.
// Dataflow: S and keys never leave the CU (r6 lost 60+ us to their HBM
// round-trip).  Cross-block overlap: 4 resident blocks per CU in different
// phases -> hash VALU covers GEMM L2 latency (m114).
// Loss semantics = verified hash_loss: full-32-bit min over margin-breakers,
// strict top16 compare for inclusion; same MFMA accumulation order -> absmax 0.
__launch_bounds__(F16THR, 8)
__global__ void fused16(const float* __restrict__ inputs,
                        const uint16_t* __restrict__ Ybf,
                        const int* __restrict__ yidx,
                        float* __restrict__ rowSum,
                        int* __restrict__ rowCnt) {
  __shared__ __align__(16) uint16_t SH[D_PAD * SRW];   // 36,864 B
  __shared__ int      y_sh[M16];
  __shared__ uint32_t sk_sh[M16][2];

  const int t    = threadIdx.x;
  const int wave = t >> 6;
  const int lane = t & 63;
  const int l15  = lane & 15;
  const int g    = lane >> 4;
  const int row0 = blockIdx.x * M16;

  if (t < M16) {
    y_sh[t] = yidx[row0 + t];
    uint32_t r1, r2, s1, s2;
    threefry2x32(0u, 42u, 0u, (uint32_t)(row0 + t), r1, r2);
    threefry2x32(r1, r2, 0u, 1u, s1, s2);
    sk_sh[t][0] = s1; sk_sh[t][1] = s2;
  }

  // ---- stage A (bf16) into LDS tail ----
  uint16_t* A_fl = SH + A_OFF;
  for (int i = t; i < M16 * (F_DIM / 4); i += F16THR) {   // 1200 float4s
    int r  = i / 75;
    int c4 = i - r * 75;
    float4 v = *(const float4*)(inputs + (size_t)(row0 + r) * F_DIM + c4 * 4);
    ushort4 o;
    o.x = f2bf(v.x); o.y = f2bf(v.y); o.z = f2bf(v.z); o.w = f2bf(v.w);
    *(ushort4*)&A_fl[r * LDA + c4 * 4] = o;
  }
  for (int i = t; i < M16 * 7; i += F16THR) {             // zero pad 300..328
    int r = i / 7, p = i - r * 7;
    *(ushort4*)&A_fl[r * LDA + 300 + p * 4] = (ushort4){0, 0, 0, 0};
  }
  __syncthreads();

  const uint16_t* aBase = A_fl + l15 * LDA + g * 8;

  // ---- GEMM half 1: cols [wave*64, wave*64+64) ; S0 write is below A_OFF ----
  {
    f32x4 acc[4];
#pragma unroll
    for (int nt = 0; nt < 4; ++nt) acc[nt] = (f32x4){0.f, 0.f, 0.f, 0.f};
    const uint16_t* gBp = Ybf + (size_t)(wave * 64 + l15) * F_PAD + g * 8;
#pragma unroll 2
    for (int ks = 0; ks < F_PAD / 32; ++ks) {
      short8 b[4], a;
#pragma unroll
      for (int nt = 0; nt < 4; ++nt)
        b[nt] = *(const short8*)(gBp + (size_t)nt * 16 * F_PAD + ks * 32);
      a = *(const short8*)(aBase + ks * 32);
#pragma unroll
      for (int nt = 0; nt < 4; ++nt)
        acc[nt] = __builtin_amdgcn_mfma_f32_16x16x32_bf16(a, b[nt], acc[nt], 0, 0, 0);
    }
#pragma unroll
    for (int nt = 0; nt < 4; ++nt) {
      const int col = wave * 64 + nt * 16 + l15;
#pragma unroll
      for (int p = 0; p < 2; ++p) {
        uint32_t lo = f2bf(acc[nt][2 * p]);       // row g*4 + 2p   (even)
        uint32_t hi = f2bf(acc[nt][2 * p + 1]);   // row g*4 + 2p+1 (odd)
        *(uint32_t*)&SH[col * SRW + g * 4 + 2 * p] = (hi << 16) | lo;
      }
    }
  }

  // ---- GEMM half 2: cols [512 + wave*64, ...) ; acc held across barrier ----
  f32x4 acc1[4];
#pragma unroll
  for (int nt = 0; nt < 4; ++nt) acc1[nt] = (f32x4){0.f, 0.f, 0.f, 0.f};
  {
    const uint16_t* gBp = Ybf + (size_t)(512 + wave * 64 + l15) * F_PAD + g * 8;
#pragma unroll 2
    for (int ks = 0; ks < F_PAD / 32; ++ks) {
      short8 b[4], a;
#pragma unroll
      for (int nt = 0; nt < 4; ++nt)
        b[nt] = *(const short8*)(gBp + (size_t)nt * 16 * F_PAD + ks * 32);
      a = *(const short8*)(aBase + ks * 32);
#pragma unroll
      for (int nt = 0; nt < 4; ++nt)
        acc1[nt] = __builtin_amdgcn_mfma_f32_16x16x32_bf16(a, b[nt], acc1[nt], 0, 0, 0);
    }
  }
  __syncthreads();   // everyone done reading A -> safe to overwrite tail with S1

#pragma unroll
  for (int nt = 0; nt < 4; ++nt) {
    const int col = 512 + wave * 64 + nt * 16 + l15;
#pragma unroll
    for (int p = 0; p < 2; ++p) {
      uint32_t lo = f2bf(acc1[nt][2 * p]);
      uint32_t hi = f2bf(acc1[nt][2 * p + 1]);
      *(uint32_t*)&SH[col * SRW + g * 4 + 2 * p] = (hi << 16) | lo;
    }
  }
  __syncthreads();   // S complete in LDS

  // ---- hash + loss: one row-pair per wave (verified hash_loss semantics) ----
  {
    const int rA = row0 + 2 * wave;
    const int yA = __builtin_amdgcn_readfirstlane(y_sh[2 * wave]);
    const int yB = __builtin_amdgcn_readfirstlane(y_sh[2 * wave + 1]);
    const uint32_t a1 = __builtin_amdgcn_readfirstlane(sk_sh[2 * wave][0]);
    const uint32_t a2 = __builtin_amdgcn_readfirstlane(sk_sh[2 * wave][1]);
    const uint32_t b1 = __builtin_amdgcn_readfirstlane(sk_sh[2 * wave + 1][0]);
    const uint32_t b2 = __builtin_amdgcn_readfirstlane(sk_sh[2 * wave + 1][1]);
    const TFSched sA = tf_make(a1, a2);
    const TFSched sB = tf_make(b1, b2);
    const float apA = bf2f((uint16_t)__builtin_amdgcn_readfirstlane(
        (uint32_t)SH[yA * SRW + 2 * wave]));
    const float apB = bf2f((uint16_t)__builtin_amdgcn_readfirstlane(
        (uint32_t)SH[yB * SRW + 2 * wave + 1]));

    uint32_t skAB[16];               // lo16 = top16(keyA), hi16 = top16(keyB)
    uint32_t pkA = 0xFFFFFFFFu, pkB = 0xFFFFFFFFu;
#pragma unroll
    for (int q = 0; q < 16; ++q) {
      const int c = q * 64 + lane;
      uint32_t kA = tf_hash(sA, (uint32_t)c);
      uint32_t kB = tf_hash(sB, (uint32_t)c);
      skAB[q] = (kA >> 16) | (kB & 0xFFFF0000u);
      const uint32_t s32 = *(const uint32_t*)&SH[c * SRW + 2 * wave];
      const float anA = bf2f_lo(s32);
      const float anB = bf2f_hi(s32);
      if ((c < D_CLS) && (c != yA) && (apA - anA) > MARGIN) {
        pkA = (kA < pkA) ? kA : pkA;
      }
      if ((c < D_CLS) && (c != yB) && (apB - anB) > MARGIN) {
        pkB = (kB < pkB) ? kB : pkB;
      }
    }
#pragma unroll
    for (int off = 1; off < 64; off <<= 1) {
      uint32_t oA = __shfl_xor(pkA, off, 64);
      uint32_t oB = __shfl_xor(pkB, off, 64);
      pkA = (oA < pkA) ? oA : pkA;
      pkB = (oB < pkB) ? oB : pkB;
    }
    const uint32_t pA16 = pkA >> 16;
    const uint32_t pB16 = pkB >> 16;

    float smA = 0.f, smB = 0.f; int ctA = 0, ctB = 0;
#pragma unroll
    for (int q = 0; q < 16; ++q) {
      const int c = q * 64 + lane;
      const uint32_t s32 = *(const uint32_t*)&SH[c * SRW + 2 * wave];
      const float anA = bf2f_lo(s32);
      const float anB = bf2f_hi(s32);
      if ((c < D_CLS) && (c != yA) && (skAB[q] & 0xFFFFu) < pA16) {
        smA += MARGIN + anA - apA; ctA += 1;
      }
      if ((c < D_CLS) && (c != yB) && (skAB[q] >> 16) < pB16) {
        smB += MARGIN + anB - apB; ctB += 1;
      }
    }
#pragma unroll
    for (int off = 1; off < 64; off <<= 1) {
      smA += __shfl_xor(smA, off, 64);
      smB += __shfl_xor(smB, off, 64);
      ctA += __shfl_xor(ctA, off, 64);
      ctB += __shfl_xor(ctB, off, 64);
    }
    if (lane == 0) {
      rowSum[rA]     = smA;
      rowCnt[rA]     = ctA + (pkA != 0xFFFFFFFFu ? 1 : 0);
      rowSum[rA + 1] = smB;
      rowCnt[rA + 1] = ctB + (pkB != 0xFFFFFFFFu ? 1 : 0);
    }
  }
}

// ============ two-stage reduction ============
__global__ void reduce_part(const float* __restrict__ rowSum,
                            const int* __restrict__ rowCnt,
                            float* __restrict__ pS, int* __restrict__ pC) {
  __shared__ float ss[4];
  __shared__ int   sc[4];
  const int base = blockIdx.x * (N_ROWS / NPART);
  float s = 0.f; int c = 0;
  for (int i = threadIdx.x; i < N_ROWS / NPART; i += 256) {
    s += rowSum[base + i];
    c += rowCnt[base + i];
  }
#pragma unroll
  for (int off = 32; off > 0; off >>= 1) {
    s += __shfl_down(s, (unsigned)off, 64);
    c += __shfl_down(c, (unsigned)off, 64);
  }
  int wid = threadIdx.x >> 6, lane = threadIdx.x & 63;
  if (lane == 0) { ss[wid] = s; sc[wid] = c; }
  __syncthreads();
  if (threadIdx.x == 0) {
    pS[blockIdx.x] = ss[0] + ss[1] + ss[2] + ss[3];
    pC[blockIdx.x] = sc[0] + sc[1] + sc[2] + sc[3];
  }
}

__global__ void reduce_final(const float* __restrict__ pS,
                             const int* __restrict__ pC,
                             float* __restrict__ out) {
  const int lane = threadIdx.x;
  float s = (lane < NPART) ? pS[lane] : 0.f;
  int   c = (lane < NPART) ? pC[lane] : 0;
#pragma unroll
  for (int off = 32; off > 0; off >>= 1) {
    s += __shfl_down(s, (unsigned)off, 64);
    c += __shfl_down(c, (unsigned)off, 64);
  }
  if (lane == 0) out[0] = s / (float)(c < 1 ? 1 : c);
}

extern "C" void kernel_launch(void* const* d_in, const int* in_sizes, int n_in,
                              void* d_out, int out_size, void* d_ws, size_t ws_size,
                              hipStream_t stream) {
  const float* inputs = (const float*)d_in[0];
  const float* Y      = (const float*)d_in[1];
  const int*   yidx   = (const int*)d_in[2];
  float* out = (float*)d_out;

  char* ws = (char*)d_ws;
  size_t off = 0;
  uint16_t* Ybf    = (uint16_t*)(ws + off); off += (size_t)D_PAD * F_PAD * 2;
  float*    rowSum = (float*)(ws + off);    off += (size_t)N_ROWS * 4;
  int*      rowCnt = (int*)(ws + off);      off += (size_t)N_ROWS * 4;
  float*    pS     = (float*)(ws + off);    off += (size_t)NPART * 4;
  int*      pC     = (int*)(ws + off);      off += (size_t)NPART * 4;

  hipLaunchKernelGGL(prep, dim3((D_PAD * F_PAD + 255) / 256), dim3(256),
                     0, stream, Y, Ybf);
  hipLaunchKernelGGL(fused16, dim3(N_ROWS / M16), dim3(F16THR),
                     0, stream, inputs, Ybf, yidx, rowSum, rowCnt);
  hipLaunchKernelGGL(reduce_part, dim3(NPART), dim3(256), 0, stream,
                     rowSum, rowCnt, pS, pC);
  hipLaunchKernelGGL(reduce_final, dim3(1), dim3(64), 0, stream, pS, pC, out);
}

// Round 8
// 137.044 us; speedup vs baseline: 1.4085x; 1.4085x over previous
//
#include <hip/hip_runtime.h>
#include <stdint.h>

#define N_ROWS 32768
#define D_CLS  1000
#define D_PAD  1024
#define F_DIM  300
#define F_PAD  320
#define MARGIN 0.1f

// ---- persistent-A GEMM params (K1) ----
#define BM     128
#define BN     128
#define BK     64
#define GTHR   512           // 8 waves: 4 M-groups x 2 N-groups
#define LDTA   328           // A LDS row stride (300 + 28 pad, 16B aligned)
#define LDTB   72            // B LDS row stride (64 + 8 pad)

// ---- fused fallback params ----
#define M_PB   32
#define NTHR   512
#define NT_PW  8
#define MT_PB  2
#define LDA    328
#define SROW   34

#define NPART  32            // reduce stage-1 blocks

typedef short short8 __attribute__((ext_vector_type(8)));
typedef float f32x4  __attribute__((ext_vector_type(4)));

__device__ __forceinline__ uint32_t rotl32(uint32_t x, int r) {
  return (x << r) | (x >> (32 - r));
}

// JAX threefry2x32 (20 rounds) — bit-exact
__device__ __forceinline__ void threefry2x32(uint32_t k0, uint32_t k1,
                                             uint32_t x0, uint32_t x1,
                                             uint32_t& o0, uint32_t& o1) {
  uint32_t k2 = k0 ^ k1 ^ 0x1BD11BDAu;
  x0 += k0; x1 += k1;
#define TF_R(r) { x0 += x1; x1 = rotl32(x1, (r)); x1 ^= x0; }
  TF_R(13) TF_R(15) TF_R(26) TF_R(6)
  x0 += k1; x1 += k2 + 1u;
  TF_R(17) TF_R(29) TF_R(16) TF_R(24)
  x0 += k2; x1 += k0 + 2u;
  TF_R(13) TF_R(15) TF_R(26) TF_R(6)
  x0 += k0; x1 += k1 + 3u;
  TF_R(17) TF_R(29) TF_R(16) TF_R(24)
  x0 += k1; x1 += k2 + 4u;
  TF_R(13) TF_R(15) TF_R(26) TF_R(6)
  x0 += k2; x1 += k0 + 5u;
#undef TF_R
  o0 = x0; o1 = x1;
}

// Hoisted-schedule threefry (r17-verified): same bits, keys precomputed once,
// rotates via v_alignbit_b32.
struct TFSched {
  uint32_t k0, k1, k2, k2p1, k0p2, k1p3, k2p4, k0p5;
};
__device__ __forceinline__ TFSched tf_make(uint32_t k0, uint32_t k1) {
  TFSched s;
  s.k0 = k0; s.k1 = k1;
  s.k2 = k0 ^ k1 ^ 0x1BD11BDAu;
  s.k2p1 = s.k2 + 1u; s.k0p2 = k0 + 2u; s.k1p3 = k1 + 3u;
  s.k2p4 = s.k2 + 4u; s.k0p5 = k0 + 5u;
  return s;
}
__device__ __forceinline__ uint32_t tf_hash(const TFSched& s, uint32_t c) {
  uint32_t x0 = s.k0, x1 = c + s.k1;
#define TFH(r) { x0 += x1; x1 = __builtin_amdgcn_alignbit(x1, x1, 32 - (r)); x1 ^= x0; }
  TFH(13) TFH(15) TFH(26) TFH(6)
  x0 += s.k1; x1 += s.k2p1;
  TFH(17) TFH(29) TFH(16) TFH(24)
  x0 += s.k2; x1 += s.k0p2;
  TFH(13) TFH(15) TFH(26) TFH(6)
  x0 += s.k0; x1 += s.k1p3;
  TFH(17) TFH(29) TFH(16) TFH(24)
  x0 += s.k1; x1 += s.k2p4;
  TFH(13) TFH(15) TFH(26) TFH(6)
  x0 += s.k2; x1 += s.k0p5;
#undef TFH
  return x0 ^ x1;
}

__device__ __forceinline__ uint16_t f2bf(float f) {   // RNE fp32 -> bf16
  uint32_t u = __builtin_bit_cast(uint32_t, f);
  return (uint16_t)((u + 0x7FFFu + ((u >> 16) & 1u)) >> 16);
}
__device__ __forceinline__ float bf2f(uint16_t v) {
  return __builtin_bit_cast(float, (uint32_t)v << 16);
}
__device__ __forceinline__ float bf2f_lo(uint32_t v) {
  return __builtin_bit_cast(float, v << 16);
}
__device__ __forceinline__ float bf2f_hi(uint32_t v) {
  return __builtin_bit_cast(float, v & 0xFFFF0000u);
}

// prep: Y fp32 -> Ybf bf16 (zero-padded) AND per-row subkeys (merged kernels)
__global__ void prep(const float* __restrict__ Y, uint16_t* __restrict__ Ybf,
                     uint32_t* __restrict__ subk) {
  int i = blockIdx.x * 256 + threadIdx.x;
  if (i < D_PAD * F_PAD) {
    int j = i / F_PAD;
    int k = i - j * F_PAD;
    float v = (j < D_CLS && k < F_DIM) ? Y[j * F_DIM + k] : 0.f;
    Ybf[i] = f2bf(v);
  }
  if (i < N_ROWS) {
    uint32_t r1, r2, s1, s2;
    threefry2x32(0u, 42u, 0u, (uint32_t)i, r1, r2);
    threefry2x32(r1, r2, 0u, 1u, s1, s2);
    subk[2 * i]     = s1;
    subk[2 * i + 1] = s2;
  }
}

// ====== K1: persistent-A MFMA GEMM (round-0-verified, 40us). Block owns 128
//        rows; A staged ONCE in LDS, loop over 8 N-tiles with B double-buffered.
__launch_bounds__(GTHR, 1)
__global__ void gemm_s(const float* __restrict__ inputs,
                       const uint16_t* __restrict__ Ybf,
                       uint32_t* __restrict__ Spair) {
  __shared__ __align__(16) uint16_t A_lds[BM * LDTA];     // 83,968 B
  __shared__ __align__(16) uint16_t B_lds[2][BN * LDTB];  // 36,864 B

  const int t    = threadIdx.x;
  const int wave = t >> 6;
  const int lane = t & 63;
  const int l15  = lane & 15;
  const int g    = lane >> 4;
  const int wm   = wave >> 1;
  const int wn   = wave & 1;
  const int r0   = blockIdx.x * BM;

  for (int i = t; i < BM * (F_DIM / 4); i += GTHR) {
    int r  = i / 75;
    int c4 = i - r * 75;
    float4 v = *(const float4*)(inputs + (size_t)(r0 + r) * F_DIM + c4 * 4);
    ushort4 o;
    o.x = f2bf(v.x); o.y = f2bf(v.y); o.z = f2bf(v.z); o.w = f2bf(v.w);
    *(ushort4*)&A_lds[r * LDTA + c4 * 4] = o;
  }
  for (int i = t; i < BM * 7; i += GTHR) {
    int r = i / 7, p = i - r * 7;
    *(ushort4*)&A_lds[r * LDTA + 300 + p * 4] = (ushort4){0, 0, 0, 0};
  }

  const int brow = t >> 3, bkof = t & 7;
  short8 bv[2];
  auto LOADB = [&](int tile) {
    const int c0 = (tile / 5) * BN;
    const int k0 = (tile % 5) * BK;
#pragma unroll
    for (int j = 0; j < 2; ++j)
      bv[j] = *(const short8*)(Ybf + (size_t)(c0 + j * 64 + brow) * F_PAD + k0 + bkof * 8);
  };
  auto WRITEB = [&](int buf) {
#pragma unroll
    for (int j = 0; j < 2; ++j)
      *(short8*)&B_lds[buf][(j * 64 + brow) * LDTB + bkof * 8] = bv[j];
  };

  f32x4 acc[2][4];
#pragma unroll
  for (int mt = 0; mt < 2; ++mt)
#pragma unroll
    for (int nt = 0; nt < 4; ++nt) acc[mt][nt] = (f32x4){0.f, 0.f, 0.f, 0.f};

  LOADB(0);
  __syncthreads();
  WRITEB(0);
  __syncthreads();

  const int NT = 8 * 5;
#pragma unroll 1
  for (int tile = 0; tile < NT; ++tile) {
    const int kt = tile % 5;
    if (tile < NT - 1) LOADB(tile + 1);
    const uint16_t* Bc = B_lds[tile & 1];
#pragma unroll
    for (int ks = 0; ks < 2; ++ks) {
      short8 a[2], b[4];
#pragma unroll
      for (int mt = 0; mt < 2; ++mt)
        a[mt] = *(const short8*)&A_lds[(wm * 32 + mt * 16 + l15) * LDTA + kt * BK + ks * 32 + g * 8];
#pragma unroll
      for (int nt = 0; nt < 4; ++nt)
        b[nt] = *(const short8*)&Bc[(wn * 64 + nt * 16 + l15) * LDTB + ks * 32 + g * 8];
#pragma unroll
      for (int mt = 0; mt < 2; ++mt)
#pragma unroll
        for (int nt = 0; nt < 4; ++nt)
          acc[mt][nt] = __builtin_amdgcn_mfma_f32_16x16x32_bf16(a[mt], b[nt], acc[mt][nt], 0, 0, 0);
    }
    if (kt == 4) {
      const int c0 = (tile / 5) * BN;
#pragma unroll
      for (int mt = 0; mt < 2; ++mt)
#pragma unroll
        for (int nt = 0; nt < 4; ++nt) {
          const int col = c0 + wn * 64 + nt * 16 + l15;
#pragma unroll
          for (int p = 0; p < 2; ++p) {
            uint32_t lo = f2bf(acc[mt][nt][2 * p]);
            uint32_t hi = f2bf(acc[mt][nt][2 * p + 1]);
            size_t rp = (size_t)(r0 >> 1) + wm * 16 + mt * 8 + g * 2 + p;
            Spair[rp * D_PAD + col] = (hi << 16) | lo;
          }
          acc[mt][nt] = (f32x4){0.f, 0.f, 0.f, 0.f};
        }
    }
    if (tile < NT - 1) {
      WRITEB((tile + 1) & 1);
      __syncthreads();
    }
  }
}

// ============ K2: hash + loss; one wave per row-pair ============
// ROUND-8 CHANGE (the only change vs the 122.6us round-0 kernel):
// launch_bounds (256,2) -> (256,6).  Round-0 counters: Occupancy 29%
// (~2.3 waves/SIMD) at 86% VALUBusy; measured 76us vs ~39us of pure issue
// -> the gap is threefry dependent-chain latency (serial add->alignbit->xor,
// ~4cy dep latency) exposed at low occupancy.  VGPR=76 fits the 6-waves/EU
// cap (85), so tripling resident waves should convert latency stalls into
// issue.  Math untouched -> absmax 0.
__launch_bounds__(256, 6)
__global__ void hash_loss(const uint32_t* __restrict__ Spair,
                          const uint32_t* __restrict__ subk,
                          const int* __restrict__ yidx,
                          float* __restrict__ rowSum,
                          int* __restrict__ rowCnt) {
  const int lane = threadIdx.x & 63;
  const int wave = threadIdx.x >> 6;
  const int rp   = blockIdx.x * 4 + wave;
  const int rA   = 2 * rp;
  const int rB   = 2 * rp + 1;

  const int yA = yidx[rA], yB = yidx[rB];
  const TFSched sA = tf_make(subk[2 * rA], subk[2 * rA + 1]);
  const TFSched sB = tf_make(subk[2 * rB], subk[2 * rB + 1]);

  const uint32_t* Sp = Spair + (size_t)rp * D_PAD;
  const float apA = bf2f_lo(Sp[yA]);
  const float apB = bf2f_hi(Sp[yB]);

  uint32_t an[16];
#pragma unroll
  for (int j = 0; j < 4; ++j) {
    uint4 v = *(const uint4*)(Sp + j * 256 + lane * 4);
    an[4 * j + 0] = v.x; an[4 * j + 1] = v.y;
    an[4 * j + 2] = v.z; an[4 * j + 3] = v.w;
  }

  uint32_t skAB[16];                 // lo16 = top16(keyA), hi16 = top16(keyB)
  uint32_t pkA = 0xFFFFFFFFu, pkB = 0xFFFFFFFFu;
#pragma unroll
  for (int q = 0; q < 16; ++q) {
    const int c = (q >> 2) * 256 + lane * 4 + (q & 3);
    uint32_t kA = tf_hash(sA, (uint32_t)c);
    uint32_t kB = tf_hash(sB, (uint32_t)c);
    skAB[q] = (kA >> 16) | (kB & 0xFFFF0000u);
    float anA = bf2f_lo(an[q]);
    float anB = bf2f_hi(an[q]);
    if ((c < D_CLS) && (c != yA) && (apA - anA) > MARGIN) {
      pkA = (kA < pkA) ? kA : pkA;
    }
    if ((c < D_CLS) && (c != yB) && (apB - anB) > MARGIN) {
      pkB = (kB < pkB) ? kB : pkB;
    }
  }
#pragma unroll
  for (int off = 1; off < 64; off <<= 1) {
    uint32_t oA = __shfl_xor(pkA, off, 64);
    uint32_t oB = __shfl_xor(pkB, off, 64);
    pkA = (oA < pkA) ? oA : pkA;
    pkB = (oB < pkB) ? oB : pkB;
  }
  const uint32_t pA16 = pkA >> 16;
  const uint32_t pB16 = pkB >> 16;

  float smA = 0.f, smB = 0.f; int ctA = 0, ctB = 0;
#pragma unroll
  for (int q = 0; q < 16; ++q) {
    const int c = (q >> 2) * 256 + lane * 4 + (q & 3);
    float anA = bf2f_lo(an[q]);
    float anB = bf2f_hi(an[q]);
    if ((c < D_CLS) && (c != yA) && (skAB[q] & 0xFFFFu) < pA16) {
      smA += MARGIN + anA - apA; ctA += 1;
    }
    if ((c < D_CLS) && (c != yB) && (skAB[q] >> 16) < pB16) {
      smB += MARGIN + anB - apB; ctB += 1;
    }
  }
#pragma unroll
  for (int off = 1; off < 64; off <<= 1) {
    smA += __shfl_xor(smA, off, 64);
    smB += __shfl_xor(smB, off, 64);
    ctA += __shfl_xor(ctA, off, 64);
    ctB += __shfl_xor(ctB, off, 64);
  }
  if (lane == 0) {
    rowSum[rA] = smA;
    rowCnt[rA] = ctA + (pkA != 0xFFFFFFFFu ? 1 : 0);
    rowSum[rB] = smB;
    rowCnt[rB] = ctB + (pkB != 0xFFFFFFFFu ? 1 : 0);
  }
}

// ============ fused fallback (round-13-verified) ============
__launch_bounds__(NTHR, 4)
__global__ void triplet_fused(const float* __restrict__ inputs,
                              const uint16_t* __restrict__ Ybf,
                              const int* __restrict__ yidx,
                              float* __restrict__ rowSum,
                              int* __restrict__ rowCnt) {
  __shared__ __align__(16) uint16_t SH[D_PAD * SROW];
  __shared__ int      y_sh[M_PB];
  __shared__ uint32_t subk_sh[M_PB][2];

  const int t    = threadIdx.x;
  const int wave = t >> 6;
  const int lane = t & 63;
  const int l15  = lane & 15;
  const int g    = lane >> 4;
  const int row0 = blockIdx.x * M_PB;
  const int colbase = wave * (NT_PW * 16);

  if (t < M_PB) {
    y_sh[t] = yidx[row0 + t];
    uint32_t r1, r2, s1, s2;
    threefry2x32(0u, 42u, 0u, (uint32_t)(row0 + t), r1, r2);
    threefry2x32(r1, r2, 0u, 1u, s1, s2);
    subk_sh[t][0] = s1; subk_sh[t][1] = s2;
  }

  uint16_t* A_fl = SH;
  for (int i = t; i < M_PB * (F_DIM / 4); i += NTHR) {
    int r  = i / 75;
    int c4 = i - r * 75;
    float4 v = *(const float4*)(inputs + (size_t)(row0 + r) * F_DIM + c4 * 4);
    ushort4 o;
    o.x = f2bf(v.x); o.y = f2bf(v.y); o.z = f2bf(v.z); o.w = f2bf(v.w);
    *(ushort4*)&A_fl[r * LDA + c4 * 4] = o;
  }
  for (int i = t; i < M_PB * 5; i += NTHR) {
    int r = i / 5, p = i - r * 5;
    *(ushort4*)&A_fl[r * LDA + 300 + p * 4] = (ushort4){0, 0, 0, 0};
  }
  __syncthreads();

  f32x4 acc[MT_PB][NT_PW];
#pragma unroll
  for (int mt = 0; mt < MT_PB; ++mt)
#pragma unroll
    for (int nt = 0; nt < NT_PW; ++nt) acc[mt][nt] = (f32x4){0.f, 0.f, 0.f, 0.f};

  const uint16_t* gB[NT_PW];
#pragma unroll
  for (int nt = 0; nt < NT_PW; ++nt) {
    int j = colbase + nt * 16 + l15;
    gB[nt] = Ybf + (size_t)j * F_PAD + (g << 3);
  }
  const uint16_t* aBase = &A_fl[l15 * LDA + (g << 3)];

#pragma unroll 2
  for (int ks = 0; ks < F_PAD / 32; ++ks) {
    short8 b[NT_PW], a[MT_PB];
#pragma unroll
    for (int nt = 0; nt < NT_PW; ++nt)
      b[nt] = *(const short8*)(gB[nt] + ks * 32);
#pragma unroll
    for (int mt = 0; mt < MT_PB; ++mt)
      a[mt] = *(const short8*)(aBase + mt * 16 * LDA + ks * 32);
#pragma unroll
    for (int mt = 0; mt < MT_PB; ++mt)
#pragma unroll
      for (int nt = 0; nt < NT_PW; ++nt)
        acc[mt][nt] = __builtin_amdgcn_mfma_f32_16x16x32_bf16(a[mt], b[nt], acc[mt][nt], 0, 0, 0);
  }

  __syncthreads();

#pragma unroll
  for (int mt = 0; mt < MT_PB; ++mt)
#pragma unroll
    for (int nt = 0; nt < NT_PW; ++nt) {
      int col = colbase + nt * 16 + l15;
#pragma unroll
      for (int p = 0; p < 2; ++p) {
        uint32_t lo = f2bf(acc[mt][nt][2 * p]);
        uint32_t hi = f2bf(acc[mt][nt][2 * p + 1]);
        *(uint32_t*)&SH[col * SROW + mt * 16 + (g << 2) + 2 * p] = (hi << 16) | lo;
      }
    }
  __syncthreads();

#pragma unroll
  for (int pr = 0; pr < 2; ++pr) {
    const int rA = wave * 4 + pr * 2;
    const int rB = rA + 1;
    const int yA = y_sh[rA], yB = y_sh[rB];
    const uint32_t a1 = subk_sh[rA][0], a2 = subk_sh[rA][1];
    const uint32_t b1 = subk_sh[rB][0], b2 = subk_sh[rB][1];
    const float apA = bf2f(SH[yA * SROW + rA]);
    const float apB = bf2f(SH[yB * SROW + rB]);

    uint32_t skA[16], skB[16];
    uint32_t pkA = 0xFFFFFFFFu, pkB = 0xFFFFFFFFu;
#pragma unroll
    for (int q = 0; q < 16; ++q) {
      const int c = q * 64 + lane;
      uint32_t xA, yAo, xB, yBo;
      threefry2x32(a1, a2, 0u, (uint32_t)c, xA, yAo);
      threefry2x32(b1, b2, 0u, (uint32_t)c, xB, yBo);
      skA[q] = xA ^ yAo;
      skB[q] = xB ^ yBo;
      float anA = bf2f(SH[c * SROW + rA]);
      float anB = bf2f(SH[c * SROW + rB]);
      if ((c < D_CLS) && (c != yA) && (apA - anA) > MARGIN) {
        pkA = (skA[q] < pkA) ? skA[q] : pkA;
      }
      if ((c < D_CLS) && (c != yB) && (apB - anB) > MARGIN) {
        pkB = (skB[q] < pkB) ? skB[q] : pkB;
      }
    }
#pragma unroll
    for (int off = 1; off < 64; off <<= 1) {
      uint32_t oA = __shfl_xor(pkA, off, 64);
      uint32_t oB = __shfl_xor(pkB, off, 64);
      pkA = (oA < pkA) ? oA : pkA;
      pkB = (oB < pkB) ? oB : pkB;
    }
    float smA = 0.f, smB = 0.f; int ctA = 0, ctB = 0;
#pragma unroll
    for (int q = 0; q < 16; ++q) {
      const int c = q * 64 + lane;
      float anA = bf2f(SH[c * SROW + rA]);
      float anB = bf2f(SH[c * SROW + rB]);
      if ((c < D_CLS) && (c != yA) && skA[q] < pkA) { smA += MARGIN + anA - apA; ctA += 1; }
      if ((c < D_CLS) && (c != yB) && skB[q] < pkB) { smB += MARGIN + anB - apB; ctB += 1; }
    }
#pragma unroll
    for (int off = 1; off < 64; off <<= 1) {
      smA += __shfl_xor(smA, off, 64);
      smB += __shfl_xor(smB, off, 64);
      ctA += __shfl_xor(ctA, off, 64);
      ctB += __shfl_xor(ctB, off, 64);
    }
    if (lane == 0) {
      rowSum[row0 + rA] = smA;
      rowCnt[row0 + rA] = ctA + (pkA != 0xFFFFFFFFu ? 1 : 0);
      rowSum[row0 + rB] = smB;
      rowCnt[row0 + rB] = ctB + (pkB != 0xFFFFFFFFu ? 1 : 0);
    }
  }
}

// ============ two-stage reduction ============
__global__ void reduce_part(const float* __restrict__ rowSum,
                            const int* __restrict__ rowCnt,
                            float* __restrict__ pS, int* __restrict__ pC) {
  __shared__ float ss[4];
  __shared__ int   sc[4];
  const int base = blockIdx.x * (N_ROWS / NPART);
  float s = 0.f; int c = 0;
  for (int i = threadIdx.x; i < N_ROWS / NPART; i += 256) {
    s += rowSum[base + i];
    c += rowCnt[base + i];
  }
#pragma unroll
  for (int off = 32; off > 0; off >>= 1) {
    s += __shfl_down(s, (unsigned)off, 64);
    c += __shfl_down(c, (unsigned)off, 64);
  }
  int wid = threadIdx.x >> 6, lane = threadIdx.x & 63;
  if (lane == 0) { ss[wid] = s; sc[wid] = c; }
  __syncthreads();
  if (threadIdx.x == 0) {
    pS[blockIdx.x] = ss[0] + ss[1] + ss[2] + ss[3];
    pC[blockIdx.x] = sc[0] + sc[1] + sc[2] + sc[3];
  }
}

__global__ void reduce_final(const float* __restrict__ pS,
                             const int* __restrict__ pC,
                             float* __restrict__ out) {
  const int lane = threadIdx.x;
  float s = (lane < NPART) ? pS[lane] : 0.f;
  int   c = (lane < NPART) ? pC[lane] : 0;
#pragma unroll
  for (int off = 32; off > 0; off >>= 1) {
    s += __shfl_down(s, (unsigned)off, 64);
    c += __shfl_down(c, (unsigned)off, 64);
  }
  if (lane == 0) out[0] = s / (float)(c < 1 ? 1 : c);
}

extern "C" void kernel_launch(void* const* d_in, const int* in_sizes, int n_in,
                              void* d_out, int out_size, void* d_ws, size_t ws_size,
                              hipStream_t stream) {
  const float* inputs = (const float*)d_in[0];
  const float* Y      = (const float*)d_in[1];
  const int*   yidx   = (const int*)d_in[2];
  float* out = (float*)d_out;

  char* ws = (char*)d_ws;
  size_t off = 0;
  uint16_t* Ybf    = (uint16_t*)(ws + off); off += (size_t)D_PAD * F_PAD * 2;
  float*    rowSum = (float*)(ws + off);    off += (size_t)N_ROWS * 4;
  int*      rowCnt = (int*)(ws + off);      off += (size_t)N_ROWS * 4;
  uint32_t* subk   = (uint32_t*)(ws + off); off += (size_t)N_ROWS * 8;
  float*    pS     = (float*)(ws + off);    off += (size_t)NPART * 4;
  int*      pC     = (int*)(ws + off);      off += (size_t)NPART * 4;
  off = (off + 255) & ~(size_t)255;
  uint32_t* Spair  = (uint32_t*)(ws + off); off += (size_t)(N_ROWS / 2) * D_PAD * 4;
  const size_t need = off;

  hipLaunchKernelGGL(prep, dim3((D_PAD * F_PAD + 255) / 256), dim3(256),
                     0, stream, Y, Ybf, subk);
  if (ws_size >= need) {
    hipLaunchKernelGGL(gemm_s, dim3(N_ROWS / BM), dim3(GTHR),
                       0, stream, inputs, Ybf, Spair);
    hipLaunchKernelGGL(hash_loss, dim3(N_ROWS / 8), dim3(256),
                       0, stream, Spair, subk, yidx, rowSum, rowCnt);
  } else {
    hipLaunchKernelGGL(triplet_fused, dim3(N_ROWS / M_PB), dim3(NTHR),
                       0, stream, inputs, Ybf, yidx, rowSum, rowCnt);
  }
  hipLaunchKernelGGL(reduce_part, dim3(NPART), dim3(256), 0, stream,
                     rowSum, rowCnt, pS, pC);
  hipLaunchKernelGGL(reduce_final, dim3(1), dim3(64), 0, stream, pS, pC, out);
}